// Round 5
// baseline (6796.916 us; speedup 1.0000x reference)
//
#include <hip/hip_runtime.h>
#include <hip/hip_bf16.h>

// Problem constants (from reference)
#define DD   128   // D
#define TT   128   // T
#define QDIM 256   // D + T
#define KDIM 384   // 2D + T
#define KN   10    // K neighbors
#define NH   2     // heads
#define HDIM 128   // QDIM / NH
#define BLK  256

struct AttnScratch {
    float q[QDIM];
    float k[KN][QDIM];
    float v[KN][QDIM];
    float att[QDIM];
    float o[QDIM];
    float h1[DD];
    float sc[NH][KN];
    float attn[NH][KN];
};

__device__ __forceinline__ float dot4(const float* __restrict__ w,
                                      const float* __restrict__ x, int len) {
    const float4* w4 = reinterpret_cast<const float4*>(w);
    const float4* x4 = reinterpret_cast<const float4*>(x);
    float acc = 0.f;
    for (int g = 0; g < len / 4; ++g) {
        float4 a = w4[g], b = x4[g];
        acc += a.x * b.x + a.y * b.y + a.z * b.z + a.w * b.w;
    }
    return acc;
}

// One temporal-attention row. qin [QDIM] and kin [KN][KDIM] must be fully
// built in LDS and covered by a __syncthreads() BEFORE the call. Ends with
// __syncthreads(); result (DD floats) in out (LDS). Weight pointers must be
// pre-offset to the layer slice.
__device__ void attn_row(int tid,
                         const float* __restrict__ qin,
                         const float (* __restrict__ kin)[KDIM],
                         unsigned maskbits, int invalid,
                         const float* __restrict__ Wq, const float* __restrict__ bq,
                         const float* __restrict__ Wk, const float* __restrict__ bk,
                         const float* __restrict__ Wv, const float* __restrict__ bv,
                         const float* __restrict__ Wo, const float* __restrict__ bo,
                         const float* __restrict__ f1w, const float* __restrict__ f1b,
                         const float* __restrict__ f2w, const float* __restrict__ f2b,
                         AttnScratch* __restrict__ s,
                         float* __restrict__ out)
{
    // ---- Q + K/V projections ----
    {
        const int o = tid;
        s->q[o] = bq[o] + dot4(Wq + (long)o * QDIM, qin, QDIM);
        float acck[KN], accv[KN];
        const float b0 = bk[o], b1 = bv[o];
        #pragma unroll
        for (int kk = 0; kk < KN; ++kk) { acck[kk] = b0; accv[kk] = b1; }
        const float4* wk4 = reinterpret_cast<const float4*>(Wk + (long)o * KDIM);
        const float4* wv4 = reinterpret_cast<const float4*>(Wv + (long)o * KDIM);
        for (int g = 0; g < KDIM / 4; ++g) {
            float4 a = wk4[g], c = wv4[g];
            #pragma unroll
            for (int kk = 0; kk < KN; ++kk) {
                float4 x = *reinterpret_cast<const float4*>(&kin[kk][g * 4]);
                acck[kk] += a.x * x.x + a.y * x.y + a.z * x.z + a.w * x.w;
                accv[kk] += c.x * x.x + c.y * x.y + c.z * x.z + c.w * x.w;
            }
        }
        #pragma unroll
        for (int kk = 0; kk < KN; ++kk) { s->k[kk][o] = acck[kk]; s->v[kk][o] = accv[kk]; }
    }
    __syncthreads();

    // ---- scores = qh . kh / sqrt(hd) ----
    if (tid < NH * KN) {
        const int h = tid / KN, kk = tid % KN;
        const float* qh = &s->q[h * HDIM];
        const float* kh = &s->k[kk][h * HDIM];
        float acc = 0.f;
        for (int j = 0; j < HDIM; ++j) acc += qh[j] * kh[j];
        s->sc[h][kk] = acc * 0.08838834764831845f;   // 1/sqrt(128)
    }
    __syncthreads();

    // ---- masked softmax over K per head ----
    if (tid < NH) {
        float v[KN], mx = -INFINITY;
        #pragma unroll
        for (int kk = 0; kk < KN; ++kk) {
            float x = s->sc[tid][kk];
            if (maskbits & (1u << kk)) x = -1e9f;
            v[kk] = x; mx = fmaxf(mx, x);
        }
        float sum = 0.f;
        #pragma unroll
        for (int kk = 0; kk < KN; ++kk) { v[kk] = expf(v[kk] - mx); sum += v[kk]; }
        const float inv = 1.f / sum;
        #pragma unroll
        for (int kk = 0; kk < KN; ++kk) s->attn[tid][kk] = v[kk] * inv;
    }
    __syncthreads();

    // ---- attn @ V ----
    {
        const int o = tid, h = o >> 7;
        float acc = 0.f;
        #pragma unroll
        for (int kk = 0; kk < KN; ++kk) acc += s->attn[h][kk] * s->v[kk][o];
        s->att[o] = acc;
    }
    __syncthreads();

    // ---- Wo projection; zero rows with no valid neighbor ----
    {
        const int o = tid;
        float acc = bo[o] + dot4(Wo + (long)o * QDIM, s->att, QDIM);
        s->o[o] = invalid ? 0.f : acc;
    }
    __syncthreads();

    // ---- MergeLayer: fc2(relu(fc1([attn_out || src_feat]))) ----
    if (tid < DD) {
        const float* r = f1w + (long)tid * (QDIM + DD);
        float acc = f1b[tid] + dot4(r, s->o, QDIM) + dot4(r + QDIM, qin, DD);
        s->h1[tid] = fmaxf(acc, 0.f);
    }
    __syncthreads();
    if (tid < DD) {
        out[tid] = f2b[tid] + dot4(f2w + (long)tid * DD, s->h1, DD);
    }
    __syncthreads();
}

__global__ __launch_bounds__(BLK) void tgn_fused(
    const int* __restrict__ source_nodes, const float* __restrict__ timestamps,
    const int* __restrict__ nbr2, const int* __restrict__ eid2, const float* __restrict__ et2,
    const int* __restrict__ nbr1, const int* __restrict__ eid1, const float* __restrict__ et1,
    const float* __restrict__ nf, const float* __restrict__ mem, const float* __restrict__ ef,
    const float* __restrict__ tw, const float* __restrict__ tb,
    const float* __restrict__ Wq, const float* __restrict__ bq,
    const float* __restrict__ Wk, const float* __restrict__ bk,
    const float* __restrict__ Wv, const float* __restrict__ bv,
    const float* __restrict__ Wo, const float* __restrict__ bo,
    const float* __restrict__ f1w, const float* __restrict__ f1b,
    const float* __restrict__ f2w, const float* __restrict__ f2b,
    float* __restrict__ out)        // f32 output per contract (reference returns float32)
{
    __shared__ __align__(16) float s_qin[QDIM];
    __shared__ __align__(16) float s_kin[KN][KDIM];
    __shared__ __align__(16) float s_emb[KN][DD];   // hop-2 results
    __shared__ __align__(16) float s_out[DD];
    __shared__ __align__(16) float s_st[TT];        // cos(time_b) (src dt = 0)
    __shared__ AttnScratch s;
    __shared__ unsigned s_mask;
    __shared__ int s_inv;

    const int b = blockIdx.x, tid = threadIdx.x;
    const float t_src = timestamps[b];   // ts2 = repeat(timestamps, K)

    if (tid < TT) s_st[tid] = cosf(tb[tid]);
    __syncthreads();

    // ================= hop-2 rows (layer 0) =================
    for (int k = 0; k < KN; ++k) {
        const int row = b * KN + k;
        const int src = nbr2[row];
        if (tid < DD) s_qin[tid] = nf[(long)src * DD + tid] + mem[(long)src * DD + tid];
        else          s_qin[tid] = s_st[tid - DD];
        if (tid == 0) {
            unsigned m = 0;
            for (int kk = 0; kk < KN; ++kk)
                if (nbr1[row * KN + kk] == 0) m |= (1u << kk);
            int inv = (m == ((1u << KN) - 1));
            if (inv) m &= ~(1u << (KN - 1));
            s_mask = m; s_inv = inv;
        }
        for (int w = tid; w < KN * (KDIM / 4); w += BLK) {
            const int kk = w / (KDIM / 4);
            const int e  = (w % (KDIM / 4)) * 4;
            float4 val;
            if (e < DD) {
                const long nb = nbr1[row * KN + kk];
                const float4 a = *(const float4*)&nf[nb * DD + e];
                const float4 c = *(const float4*)&mem[nb * DD + e];
                val = make_float4(a.x + c.x, a.y + c.y, a.z + c.z, a.w + c.w);
            } else if (e < 2 * DD) {
                const long eid = eid1[row * KN + kk];
                val = *(const float4*)&ef[eid * DD + (e - DD)];
            } else {
                const int t = e - 2 * DD;
                const float dt = t_src - et1[row * KN + kk];
                val = make_float4(cosf(dt * tw[t]     + tb[t]),
                                  cosf(dt * tw[t + 1] + tb[t + 1]),
                                  cosf(dt * tw[t + 2] + tb[t + 2]),
                                  cosf(dt * tw[t + 3] + tb[t + 3]));
            }
            *(float4*)&s_kin[kk][e] = val;
        }
        __syncthreads();
        attn_row(tid, s_qin, s_kin, s_mask, s_inv,
                 Wq, bq, Wk, bk, Wv, bv, Wo, bo, f1w, f1b, f2w, f2b,
                 &s, s_emb[k]);
    }

    // ================= top row (layer 1) =================
    {
        const int src = source_nodes[b];
        if (tid < DD) s_qin[tid] = nf[(long)src * DD + tid] + mem[(long)src * DD + tid];
        else          s_qin[tid] = s_st[tid - DD];
        if (tid == 0) {
            unsigned m = 0;
            for (int kk = 0; kk < KN; ++kk)
                if (nbr2[b * KN + kk] == 0) m |= (1u << kk);
            int inv = (m == ((1u << KN) - 1));
            if (inv) m &= ~(1u << (KN - 1));
            s_mask = m; s_inv = inv;
        }
        for (int w = tid; w < KN * (KDIM / 4); w += BLK) {
            const int kk = w / (KDIM / 4);
            const int e  = (w % (KDIM / 4)) * 4;
            float4 val;
            if (e < DD) {
                val = *(const float4*)&s_emb[kk][e];
            } else if (e < 2 * DD) {
                const long eid = eid2[b * KN + kk];
                val = *(const float4*)&ef[eid * DD + (e - DD)];
            } else {
                const int t = e - 2 * DD;
                const float dt = t_src - et2[b * KN + kk];
                val = make_float4(cosf(dt * tw[t]     + tb[t]),
                                  cosf(dt * tw[t + 1] + tb[t + 1]),
                                  cosf(dt * tw[t + 2] + tb[t + 2]),
                                  cosf(dt * tw[t + 3] + tb[t + 3]));
            }
            *(float4*)&s_kin[kk][e] = val;
        }
        __syncthreads();
        attn_row(tid, s_qin, s_kin, s_mask, s_inv,
                 Wq + QDIM * QDIM, bq + QDIM,
                 Wk + QDIM * KDIM, bk + QDIM,
                 Wv + QDIM * KDIM, bv + QDIM,
                 Wo + QDIM * QDIM, bo + QDIM,
                 f1w + DD * (QDIM + DD), f1b + DD,
                 f2w + DD * DD, f2b + DD,
                 &s, s_out);
        if (tid < DD) out[(long)b * DD + tid] = s_out[tid];
    }
}

extern "C" void kernel_launch(void* const* d_in, const int* in_sizes, int n_in,
                              void* d_out, int out_size, void* d_ws, size_t ws_size,
                              hipStream_t stream) {
    const float* nf  = (const float*)d_in[0];
    const float* mem = (const float*)d_in[1];
    const float* ef  = (const float*)d_in[2];
    const float* tw  = (const float*)d_in[3];
    const float* tb  = (const float*)d_in[4];
    const float* Wq  = (const float*)d_in[5];
    const float* bq  = (const float*)d_in[6];
    const float* Wk  = (const float*)d_in[7];
    const float* bk  = (const float*)d_in[8];
    const float* Wv  = (const float*)d_in[9];
    const float* bv  = (const float*)d_in[10];
    const float* Wo  = (const float*)d_in[11];
    const float* bo  = (const float*)d_in[12];
    const float* f1w = (const float*)d_in[13];
    const float* f1b = (const float*)d_in[14];
    const float* f2w = (const float*)d_in[15];
    const float* f2b = (const float*)d_in[16];
    const int* src_nodes = (const int*)d_in[17];
    const float* ts  = (const float*)d_in[18];
    const int* nbr2  = (const int*)d_in[19];
    const int* eid2  = (const int*)d_in[20];
    const float* et2 = (const float*)d_in[21];
    const int* nbr1  = (const int*)d_in[22];
    const int* eid1  = (const int*)d_in[23];
    const float* et1 = (const float*)d_in[24];

    const int B = in_sizes[17];   // 2048

    tgn_fused<<<B, BLK, 0, stream>>>(
        src_nodes, ts, nbr2, eid2, et2, nbr1, eid1, et1,
        nf, mem, ef, tw, tb,
        Wq, bq, Wk, bk, Wv, bv, Wo, bo,
        f1w, f1b, f2w, f2b,
        (float*)d_out);
}